// Round 9
// baseline (78.710 us; speedup 1.0000x reference)
//
#include <hip/hip_runtime.h>

#define NPTS 8192
#define NB 2
#define NTILES 256               // 32-point B-tiles per (dir,batch)
#define FMAX 3.4028235e38f

typedef __attribute__((ext_vector_type(8)))  short short8;
typedef __attribute__((ext_vector_type(16))) float f32x16;

__device__ __forceinline__ unsigned short bf16_rne(float f) {
    unsigned u = __float_as_uint(f);
    unsigned r = u + 0x7FFFu + ((u >> 16) & 1u);
    return (unsigned short)(r >> 16);
}
__device__ __forceinline__ float bf16_tof(unsigned short h) {
    return __uint_as_float(((unsigned)h) << 16);
}

// Build all B-fragment records once. Record = 32 B, K=16 bf16 slots:
//   k0..2=yh(-2y) k3..5=yh k6..8=yl k9,10=1.0 k11=b2h k12=b2l k13..15=0
// (verified in-situ R7/R8: absmax 0.0156 vs 0.047 threshold)
__global__ __launch_bounds__(256) void _chamfer_prep(const float* __restrict__ x,
                                                     const float* __restrict__ y,
                                                     unsigned char* __restrict__ rec) {
    const int r = blockIdx.x * 256 + (int)threadIdx.x;  // 0..32767
    const int dir = r >> 14, batch = (r >> 13) & 1, p = r & (NPTS - 1);
    const float* src = (dir ? x : y) + ((size_t)batch * NPTS + p) * 3;
    const float vx = src[0], vy = src[1], vz = src[2];
    const float nx = -2.f*vx, ny = -2.f*vy, nz = -2.f*vz;
    const unsigned short h0 = bf16_rne(nx), h1 = bf16_rne(ny), h2 = bf16_rne(nz);
    const unsigned short l0 = bf16_rne(nx - bf16_tof(h0));
    const unsigned short l1 = bf16_rne(ny - bf16_tof(h1));
    const unsigned short l2 = bf16_rne(nz - bf16_tof(h2));
    const float b2 = vx*vx + vy*vy + vz*vz;
    const unsigned short bh = bf16_rne(b2);
    const unsigned short bl = bf16_rne(b2 - bf16_tof(bh));
    uint4 w0, w1;
    w0.x = (unsigned)h0 | ((unsigned)h1 << 16);
    w0.y = (unsigned)h2 | ((unsigned)h0 << 16);
    w0.z = (unsigned)h1 | ((unsigned)h2 << 16);
    w0.w = (unsigned)l0 | ((unsigned)l1 << 16);
    w1.x = (unsigned)l2 | (0x3F80u << 16);
    w1.y = 0x3F80u | ((unsigned)bh << 16);
    w1.z = (unsigned)bl;
    w1.w = 0u;
    uint4* dst = (uint4*)(rec + (((size_t)(dir * NB + batch) * NTILES + (p >> 5)) * 1024
                                 + (size_t)(p & 31) * 32));
    dst[0] = w0; dst[1] = w1;
}

// Grid (64, NB, 2): 256 blocks, 4 waves each. Wave = one 32-row m-tile,
// sweeps ALL 256 B-fragments (full opposite cloud) from L2 with a 4-deep
// register prefetch pipeline. Row-min lives in C-layout regs; per-wave
// stride-33 LDS transpose finishes the row reduce; writes d_out directly.
__global__ __launch_bounds__(256) void _chamfer_main(const float* __restrict__ x,
                                                     const float* __restrict__ y,
                                                     const unsigned char* __restrict__ rec,
                                                     float* __restrict__ out) {
    const int msuper = blockIdx.x;      // 0..63
    const int batch  = blockIdx.y;      // 0..1
    const int dir    = blockIdx.z;      // 0..1

    const float* A = dir ? y : x;

    __shared__ float red[4 * 32 * 33];  // per-wave regions, stride-33

    const int t    = (int)threadIdx.x;
    const int lane = t & 63;
    const int wv   = t >> 6;
    const int col  = lane & 31;
    const int kg   = lane >> 5;
    const int mtile = msuper * 4 + wv;

    // ---- A-fragment: one x-point per lane (bf16x3 split + |a|^2 hi/lo) ----
    const int mrow = mtile * 32 + col;
    short8 afrag;
    {
        const float* ap = A + (size_t)batch * NPTS * 3 + (size_t)mrow * 3;
        const float vx = ap[0], vy = ap[1], vz = ap[2];
        const unsigned short h0 = bf16_rne(vx), h1 = bf16_rne(vy), h2 = bf16_rne(vz);
        const unsigned short l0 = bf16_rne(vx - bf16_tof(h0));
        const unsigned short l1 = bf16_rne(vy - bf16_tof(h1));
        const unsigned short l2 = bf16_rne(vz - bf16_tof(h2));
        const float a2 = vx*vx + vy*vy + vz*vz;
        const unsigned short ah = bf16_rne(a2);
        const unsigned short al = bf16_rne(a2 - bf16_tof(ah));
        const unsigned short ONE = 0x3F80u;
        if (kg == 0) {
            afrag[0]=(short)h0; afrag[1]=(short)h1; afrag[2]=(short)h2;
            afrag[3]=(short)l0; afrag[4]=(short)l1; afrag[5]=(short)l2;
            afrag[6]=(short)h0; afrag[7]=(short)h1;
        } else {
            afrag[0]=(short)h2; afrag[1]=(short)ah; afrag[2]=(short)al;
            afrag[3]=(short)ONE; afrag[4]=(short)ONE;
            afrag[5]=0; afrag[6]=0; afrag[7]=0;
        }
    }

    f32x16 z, rm;
    #pragma unroll
    for (int q = 0; q < 16; ++q) { z[q] = 0.f; rm[q] = FMAX; }

    // ---- full sweep: 256 fragments, 4-deep register prefetch ----
    const unsigned char* rbase = rec
        + (size_t)(dir * NB + batch) * NTILES * 1024
        + (size_t)col * 32 + (size_t)kg * 16;

    short8 c0 = *(const short8*)(rbase);
    short8 c1 = *(const short8*)(rbase + 1024);
    short8 c2 = *(const short8*)(rbase + 2048);
    short8 c3 = *(const short8*)(rbase + 3072);

    for (int tt = 4; tt < NTILES; tt += 4) {
        const short8 n0 = *(const short8*)(rbase + (size_t)tt * 1024);
        const short8 n1 = *(const short8*)(rbase + (size_t)tt * 1024 + 1024);
        const short8 n2 = *(const short8*)(rbase + (size_t)tt * 1024 + 2048);
        const short8 n3 = *(const short8*)(rbase + (size_t)tt * 1024 + 3072);
        const f32x16 d0 = __builtin_amdgcn_mfma_f32_32x32x16_bf16(afrag, c0, z, 0, 0, 0);
        const f32x16 d1 = __builtin_amdgcn_mfma_f32_32x32x16_bf16(afrag, c1, z, 0, 0, 0);
        const f32x16 d2 = __builtin_amdgcn_mfma_f32_32x32x16_bf16(afrag, c2, z, 0, 0, 0);
        const f32x16 d3 = __builtin_amdgcn_mfma_f32_32x32x16_bf16(afrag, c3, z, 0, 0, 0);
        #pragma unroll
        for (int q = 0; q < 16; ++q) {
            rm[q] = fminf(fminf(rm[q], d0[q]), d1[q]);   // v_min3_f32
            rm[q] = fminf(fminf(rm[q], d2[q]), d3[q]);
        }
        c0 = n0; c1 = n1; c2 = n2; c3 = n3;
    }
    {   // tail
        const f32x16 d0 = __builtin_amdgcn_mfma_f32_32x32x16_bf16(afrag, c0, z, 0, 0, 0);
        const f32x16 d1 = __builtin_amdgcn_mfma_f32_32x32x16_bf16(afrag, c1, z, 0, 0, 0);
        const f32x16 d2 = __builtin_amdgcn_mfma_f32_32x32x16_bf16(afrag, c2, z, 0, 0, 0);
        const f32x16 d3 = __builtin_amdgcn_mfma_f32_32x32x16_bf16(afrag, c3, z, 0, 0, 0);
        #pragma unroll
        for (int q = 0; q < 16; ++q) {
            rm[q] = fminf(fminf(rm[q], d0[q]), d1[q]);
            rm[q] = fminf(fminf(rm[q], d2[q]), d3[q]);
        }
    }

    // ---- per-wave row reduce: C layout row=(q&3)+8*(q>>2)+4*kg, col=lane&31 ----
    #pragma unroll
    for (int q = 0; q < 16; ++q) {
        const int r = (q & 3) + 8 * (q >> 2) + 4 * kg;
        red[wv * 1056 + r * 33 + col] = rm[q];
    }
    __syncthreads();   // cheap; orders LDS writes vs reads (incl. intra-wave)
    if (lane < 32) {
        const float* pr = red + wv * 1056 + lane * 33;
        float m = pr[0];
        #pragma unroll
        for (int c = 1; c < 32; ++c) m = fminf(m, pr[c]);
        out[((size_t)dir * NB + batch) * NPTS + (size_t)mtile * 32 + lane]
            = fmaxf(m, 0.f);
    }
}

extern "C" void kernel_launch(void* const* d_in, const int* in_sizes, int n_in,
                              void* d_out, int out_size, void* d_ws, size_t ws_size,
                              hipStream_t stream) {
    const float* x = (const float*)d_in[0];
    const float* y = (const float*)d_in[1];
    unsigned char* rec = (unsigned char*)d_ws;   // 1 MiB records
    float* out = (float*)d_out;

    _chamfer_prep<<<dim3(NB * NB * NPTS / 256), dim3(256), 0, stream>>>(x, y, rec);
    _chamfer_main<<<dim3(64, NB, 2), dim3(256), 0, stream>>>(x, y, rec, out);
}

// Round 10
// 69.194 us; speedup vs baseline: 1.1375x; 1.1375x over previous
//
#include <hip/hip_runtime.h>

#define NPTS 8192
#define NB 2
#define NTILES 256               // 32-point B-tiles per (dir,batch)
#define FPS 64                   // fragments per split (quarter of cloud)
#define FPC 16                   // fragments per staged chunk (16 KB)
#define NCH (FPS / FPC)          // 4 chunks per split
#define FMAX 3.4028235e38f
#define REC_BYTES ((size_t)2 * NB * NTILES * 1024)   // 1 MiB

typedef __attribute__((ext_vector_type(8)))  short short8;
typedef __attribute__((ext_vector_type(16))) float f32x16;

__device__ __forceinline__ unsigned short bf16_rne(float f) {
    unsigned u = __float_as_uint(f);
    unsigned r = u + 0x7FFFu + ((u >> 16) & 1u);
    return (unsigned short)(r >> 16);
}
__device__ __forceinline__ float bf16_tof(unsigned short h) {
    return __uint_as_float(((unsigned)h) << 16);
}

// Build all B-fragment records once. Record = 32 B, K=16 bf16 slots:
//   k0..2=yh(-2y) k3..5=yh k6..8=yl k9,10=1.0 k11=b2h k12=b2l k13..15=0
// (packing verified in-situ R7-R9: absmax 0.0156 vs 0.047 threshold)
__global__ __launch_bounds__(256) void _chamfer_prep(const float* __restrict__ x,
                                                     const float* __restrict__ y,
                                                     unsigned char* __restrict__ rec) {
    const int r = blockIdx.x * 256 + (int)threadIdx.x;  // 0..32767
    const int dir = r >> 14, batch = (r >> 13) & 1, p = r & (NPTS - 1);
    const float* src = (dir ? x : y) + ((size_t)batch * NPTS + p) * 3;
    const float vx = src[0], vy = src[1], vz = src[2];
    const float nx = -2.f*vx, ny = -2.f*vy, nz = -2.f*vz;
    const unsigned short h0 = bf16_rne(nx), h1 = bf16_rne(ny), h2 = bf16_rne(nz);
    const unsigned short l0 = bf16_rne(nx - bf16_tof(h0));
    const unsigned short l1 = bf16_rne(ny - bf16_tof(h1));
    const unsigned short l2 = bf16_rne(nz - bf16_tof(h2));
    const float b2 = vx*vx + vy*vy + vz*vz;
    const unsigned short bh = bf16_rne(b2);
    const unsigned short bl = bf16_rne(b2 - bf16_tof(bh));
    uint4 w0, w1;
    w0.x = (unsigned)h0 | ((unsigned)h1 << 16);
    w0.y = (unsigned)h2 | ((unsigned)h0 << 16);
    w0.z = (unsigned)h1 | ((unsigned)h2 << 16);
    w0.w = (unsigned)l0 | ((unsigned)l1 << 16);
    w1.x = (unsigned)l2 | (0x3F80u << 16);
    w1.y = 0x3F80u | ((unsigned)bh << 16);
    w1.z = (unsigned)bl;
    w1.w = 0u;
    uint4* dst = (uint4*)(rec + (((size_t)(dir * NB + batch) * NTILES + (p >> 5)) * 1024
                                 + (size_t)(p & 31) * 32));
    dst[0] = w0; dst[1] = w1;
}

// Grid (64 msuper, 4 dirbatch, 4 split) = 1024 blocks, 4 waves each
// -> 4 blocks/CU, 4 waves/SIMD. Wave = one 32-row m-tile; block sweeps its
// 64-fragment split in 4 chunks of 16 KB staged in LDS (shared by 4 waves),
// double-buffered; chunk c+1 global loads issue BEFORE compute of chunk c
// (latency hides under 16 MFMA + 256 min3). Per-wave row reduce -> partial.
__global__ __launch_bounds__(256, 4) void _chamfer_main(const float* __restrict__ x,
                                                        const float* __restrict__ y,
                                                        const unsigned char* __restrict__ rec,
                                                        float* __restrict__ part) {
    const int msuper = blockIdx.x;      // 0..63
    const int db     = blockIdx.y;      // dir*NB+batch, 0..3
    const int split  = blockIdx.z;      // 0..3
    const int dir    = db >> 1;

    const float* A = dir ? y : x;
    const int batch = db & 1;

    __shared__ unsigned char lds[2 * FPC * 1024];   // 32 KB double buffer

    const int t    = (int)threadIdx.x;
    const int lane = t & 63;
    const int wv   = t >> 6;
    const int col  = lane & 31;
    const int kg   = lane >> 5;
    const int mtile = msuper * 4 + wv;

    // ---- A-fragment: one x-point per lane (bf16x3 split + |a|^2 hi/lo) ----
    const int mrow = mtile * 32 + col;
    short8 afrag;
    {
        const float* ap = A + (size_t)batch * NPTS * 3 + (size_t)mrow * 3;
        const float vx = ap[0], vy = ap[1], vz = ap[2];
        const unsigned short h0 = bf16_rne(vx), h1 = bf16_rne(vy), h2 = bf16_rne(vz);
        const unsigned short l0 = bf16_rne(vx - bf16_tof(h0));
        const unsigned short l1 = bf16_rne(vy - bf16_tof(h1));
        const unsigned short l2 = bf16_rne(vz - bf16_tof(h2));
        const float a2 = vx*vx + vy*vy + vz*vz;
        const unsigned short ah = bf16_rne(a2);
        const unsigned short al = bf16_rne(a2 - bf16_tof(ah));
        const unsigned short ONE = 0x3F80u;
        if (kg == 0) {
            afrag[0]=(short)h0; afrag[1]=(short)h1; afrag[2]=(short)h2;
            afrag[3]=(short)l0; afrag[4]=(short)l1; afrag[5]=(short)l2;
            afrag[6]=(short)h0; afrag[7]=(short)h1;
        } else {
            afrag[0]=(short)h2; afrag[1]=(short)ah; afrag[2]=(short)al;
            afrag[3]=(short)ONE; afrag[4]=(short)ONE;
            afrag[5]=0; afrag[6]=0; afrag[7]=0;
        }
    }

    f32x16 z, rm;
    #pragma unroll
    for (int q = 0; q < 16; ++q) { z[q] = 0.f; rm[q] = FMAX; }

    // Record source for this block's split: 64 KB, in 4 chunks of 16 KB.
    const unsigned char* sbase = rec + (size_t)db * NTILES * 1024
                                     + (size_t)split * FPS * 1024;

    // Prologue: stage chunk 0 into buf 0 (stall exposed once).
    {
        const uint4* g = (const uint4*)(sbase) + t;      // t*16 B, +4 KB/pass
        uint4 r0 = g[0], r1 = g[256], r2 = g[512], r3 = g[768];
        uint4* l = (uint4*)lds + t;
        l[0] = r0; l[256] = r1; l[512] = r2; l[768] = r3;
    }
    __syncthreads();

    const unsigned char* fbase = lds + (size_t)col * 32 + (size_t)kg * 16;
    #pragma unroll
    for (int c = 0; c < NCH; ++c) {
        uint4 r0, r1, r2, r3;
        if (c + 1 < NCH) {      // issue next-chunk loads BEFORE compute
            const uint4* g = (const uint4*)(sbase + (size_t)(c + 1) * FPC * 1024) + t;
            r0 = g[0]; r1 = g[256]; r2 = g[512]; r3 = g[768];
        }
        // compute current chunk from LDS: 16 frags, unrolled by 2
        const unsigned char* fb = fbase + (size_t)(c & 1) * (FPC * 1024);
        #pragma unroll
        for (int ff = 0; ff < FPC; ff += 2) {
            const short8 b0 = *(const short8*)(fb + (size_t)ff * 1024);
            const short8 b1 = *(const short8*)(fb + (size_t)ff * 1024 + 1024);
            const f32x16 d0 = __builtin_amdgcn_mfma_f32_32x32x16_bf16(afrag, b0, z, 0, 0, 0);
            const f32x16 d1 = __builtin_amdgcn_mfma_f32_32x32x16_bf16(afrag, b1, z, 0, 0, 0);
            #pragma unroll
            for (int q = 0; q < 16; ++q)
                rm[q] = fminf(fminf(rm[q], d0[q]), d1[q]);   // v_min3_f32
        }
        if (c + 1 < NCH) {      // write next chunk into the other buffer
            uint4* l = (uint4*)(lds + (size_t)((c + 1) & 1) * (FPC * 1024)) + t;
            l[0] = r0; l[256] = r1; l[512] = r2; l[768] = r3;
        }
        __syncthreads();
    }

    // ---- per-wave row reduce: C layout row=(q&3)+8*(q>>2)+4*kg ----
    float* red = (float*)lds;           // 4 x 32 x 33 floats = 16.9 KB
    #pragma unroll
    for (int q = 0; q < 16; ++q) {
        const int r = (q & 3) + 8 * (q >> 2) + 4 * kg;
        red[wv * 1056 + r * 33 + col] = rm[q];
    }
    __syncthreads();
    if (lane < 32) {
        const float* pr = red + wv * 1056 + lane * 33;
        float m = pr[0];
        #pragma unroll
        for (int c = 1; c < 32; ++c) m = fminf(m, pr[c]);
        part[((size_t)db * 4 + split) * NPTS + (size_t)mtile * 32 + lane] = m;
    }
}

// Final: min over the 4 split partials + clamp. out = dl(2x8192) then dr(2x8192).
__global__ __launch_bounds__(256) void _chamfer_reduce(const float* __restrict__ part,
                                                       float* __restrict__ out) {
    const int w = blockIdx.x * 256 + (int)threadIdx.x;    // 0..32767
    const int db = w >> 13, i = w & (NPTS - 1);
    const float* p = part + (size_t)db * 4 * NPTS + i;
    float m = fminf(fminf(p[0], p[NPTS]), fminf(p[2 * NPTS], p[3 * NPTS]));
    out[w] = fmaxf(m, 0.f);
}

extern "C" void kernel_launch(void* const* d_in, const int* in_sizes, int n_in,
                              void* d_out, int out_size, void* d_ws, size_t ws_size,
                              hipStream_t stream) {
    const float* x = (const float*)d_in[0];
    const float* y = (const float*)d_in[1];
    unsigned char* rec = (unsigned char*)d_ws;                 // 1 MiB records
    float* part = (float*)(rec + REC_BYTES);                   // 512 KiB partials
    float* out  = (float*)d_out;

    _chamfer_prep<<<dim3(NB * NB * NPTS / 256), dim3(256), 0, stream>>>(x, y, rec);
    _chamfer_main<<<dim3(64, 4, 4), dim3(256), 0, stream>>>(x, y, rec, part);
    _chamfer_reduce<<<dim3(out_size / 256), dim3(256), 0, stream>>>(part, out);
}

// Round 11
// 65.942 us; speedup vs baseline: 1.1936x; 1.0493x over previous
//
#include <hip/hip_runtime.h>

#define NPTS 8192
#define NB 2
#define NSPLIT 8                 // B-splits per (dir,batch)
#define FPS 32                   // fragments (32-pt tiles) per split
#define MROWS 256                // m-rows per block (4 waves x 2 mtiles x 32)
#define FMAX 3.4028235e38f

typedef __attribute__((ext_vector_type(8)))  short short8;
typedef __attribute__((ext_vector_type(16))) float f32x16;

__device__ __forceinline__ unsigned short bf16_rne(float f) {
    unsigned u = __float_as_uint(f);
    unsigned r = u + 0x7FFFu + ((u >> 16) & 1u);
    return (unsigned short)(r >> 16);
}
__device__ __forceinline__ float bf16_tof(unsigned short h) {
    return __uint_as_float(((unsigned)h) << 16);
}

// Fused kernel. Grid (32 msuper, 4 db, 8 split) = 1024 blocks, 4 waves each
// -> 4 blocks/CU, 4 waves/SIMD. Block: 256 m-rows x one 1024-point B-split.
// Step 1: block converts its split's raw points (12 KB, L2-hot) into 32
//   pre-packed K=16 fragment tiles in LDS, laid out in LANE ORDER: half h of
//   record c at tile*1024 + h*512 + c*16, so the sweep's ds_read_b128 at
//   lane*16 is the canonical conflict-free pattern.
// Step 2: each wave sweeps the 32 fragments; each read feeds TWO m-tiles
//   (2 MFMA + 32 min3) halving LDS-pipe load vs 1 mtile/wave.
// Record slots: k0..2=yh(-2y) k3..5=yh k6..8=yl k9,10=1.0 k11=b2h k12=b2l
// k13..15=0  (packing verified in-situ R7-R10: absmax 0.0156 vs 0.047 thr).
__global__ __launch_bounds__(256, 4) void _chamfer_main(const float* __restrict__ x,
                                                        const float* __restrict__ y,
                                                        float* __restrict__ part) {
    const int msuper = blockIdx.x;      // 0..31
    const int db     = blockIdx.y;      // dir*NB+batch, 0..3
    const int split  = blockIdx.z;      // 0..7
    const int dir    = db >> 1;
    const int batch  = db & 1;

    const float* A = dir ? y : x;
    const float* B = dir ? x : y;

    __shared__ unsigned char lds[FPS * 1024];   // 32 KB fragments; reused for red

    const int t    = (int)threadIdx.x;
    const int lane = t & 63;
    const int wv   = t >> 6;
    const int col  = lane & 31;
    const int kg   = lane >> 5;

    // ---- step 1: convert split's 1024 B-points into LDS fragment tiles ----
    {
        const float* bsrc = B + ((size_t)batch * NPTS + (size_t)split * 1024) * 3;
        #pragma unroll
        for (int rr = 0; rr < 4; ++rr) {
            const int p = rr * 256 + t;                  // 0..1023
            const float* sp = bsrc + (size_t)p * 3;
            const float vx = sp[0], vy = sp[1], vz = sp[2];
            const float nx = -2.f*vx, ny = -2.f*vy, nz = -2.f*vz;
            const unsigned short h0 = bf16_rne(nx), h1 = bf16_rne(ny), h2 = bf16_rne(nz);
            const unsigned short l0 = bf16_rne(nx - bf16_tof(h0));
            const unsigned short l1 = bf16_rne(ny - bf16_tof(h1));
            const unsigned short l2 = bf16_rne(nz - bf16_tof(h2));
            const float b2 = vx*vx + vy*vy + vz*vz;
            const unsigned short bh = bf16_rne(b2);
            const unsigned short bl = bf16_rne(b2 - bf16_tof(bh));
            uint4 w0, w1;
            w0.x = (unsigned)h0 | ((unsigned)h1 << 16);   // k0,k1
            w0.y = (unsigned)h2 | ((unsigned)h0 << 16);   // k2,k3
            w0.z = (unsigned)h1 | ((unsigned)h2 << 16);   // k4,k5
            w0.w = (unsigned)l0 | ((unsigned)l1 << 16);   // k6,k7
            w1.x = (unsigned)l2 | (0x3F80u << 16);        // k8,k9
            w1.y = 0x3F80u | ((unsigned)bh << 16);        // k10,k11
            w1.z = (unsigned)bl;                          // k12,k13
            w1.w = 0u;                                    // k14,k15
            unsigned char* tile = lds + (size_t)(p >> 5) * 1024;
            *(uint4*)(tile + (size_t)(p & 31) * 16)       = w0;  // half 0
            *(uint4*)(tile + 512 + (size_t)(p & 31) * 16) = w1;  // half 1
        }
    }

    // ---- A-fragments: 2 m-tiles per wave (bf16x3 split + |a|^2 hi/lo) ----
    short8 af[2];
    #pragma unroll
    for (int mt = 0; mt < 2; ++mt) {
        const int mrow = msuper * MROWS + wv * 64 + mt * 32 + col;
        const float* ap = A + ((size_t)batch * NPTS + mrow) * 3;
        const float vx = ap[0], vy = ap[1], vz = ap[2];
        const unsigned short h0 = bf16_rne(vx), h1 = bf16_rne(vy), h2 = bf16_rne(vz);
        const unsigned short l0 = bf16_rne(vx - bf16_tof(h0));
        const unsigned short l1 = bf16_rne(vy - bf16_tof(h1));
        const unsigned short l2 = bf16_rne(vz - bf16_tof(h2));
        const float a2 = vx*vx + vy*vy + vz*vz;
        const unsigned short ah = bf16_rne(a2);
        const unsigned short al = bf16_rne(a2 - bf16_tof(ah));
        const unsigned short ONE = 0x3F80u;
        if (kg == 0) {
            af[mt][0]=(short)h0; af[mt][1]=(short)h1; af[mt][2]=(short)h2;
            af[mt][3]=(short)l0; af[mt][4]=(short)l1; af[mt][5]=(short)l2;
            af[mt][6]=(short)h0; af[mt][7]=(short)h1;
        } else {
            af[mt][0]=(short)h2; af[mt][1]=(short)ah; af[mt][2]=(short)al;
            af[mt][3]=(short)ONE; af[mt][4]=(short)ONE;
            af[mt][5]=0; af[mt][6]=0; af[mt][7]=0;
        }
    }

    f32x16 z, rm[2];
    #pragma unroll
    for (int q = 0; q < 16; ++q) { z[q] = 0.f; rm[0][q] = FMAX; rm[1][q] = FMAX; }

    __syncthreads();

    // ---- step 2: sweep 32 fragments; 1 ds_read : 2 MFMA : 32 min3 ----
    const unsigned char* fb = lds + (size_t)lane * 16;
    #pragma unroll 4
    for (int ff = 0; ff < FPS; ff += 2) {
        const short8 b0 = *(const short8*)(fb + (size_t)ff * 1024);
        const short8 b1 = *(const short8*)(fb + (size_t)ff * 1024 + 1024);
        #pragma unroll
        for (int mt = 0; mt < 2; ++mt) {
            const f32x16 d0 = __builtin_amdgcn_mfma_f32_32x32x16_bf16(af[mt], b0, z, 0, 0, 0);
            const f32x16 d1 = __builtin_amdgcn_mfma_f32_32x32x16_bf16(af[mt], b1, z, 0, 0, 0);
            #pragma unroll
            for (int q = 0; q < 16; ++q)
                rm[mt][q] = fminf(fminf(rm[mt][q], d0[q]), d1[q]);   // v_min3_f32
        }
    }

    // ---- per-wave row reduce, two rounds (LDS region reused) ----
    float* red = (float*)lds;            // 4 x 32 x 33 floats = 16.9 KB
    float* po  = part + ((size_t)(db * NSPLIT + split) * NPTS) + msuper * MROWS;
    #pragma unroll
    for (int mt = 0; mt < 2; ++mt) {
        __syncthreads();
        #pragma unroll
        for (int q = 0; q < 16; ++q) {
            const int r = (q & 3) + 8 * (q >> 2) + 4 * kg;   // C-layout row
            red[wv * 1056 + r * 33 + col] = rm[mt][q];
        }
        __syncthreads();
        if (lane < 32) {
            const float* pr = red + wv * 1056 + lane * 33;
            float m = pr[0];
            #pragma unroll
            for (int c = 1; c < 32; ++c) m = fminf(m, pr[c]);
            po[wv * 64 + mt * 32 + lane] = m;
        }
    }
}

// Final: min over the 8 split partials + clamp. out = dl(2x8192) then dr(2x8192).
__global__ __launch_bounds__(256) void _chamfer_reduce(const float* __restrict__ part,
                                                       float* __restrict__ out) {
    const int w = blockIdx.x * 256 + (int)threadIdx.x;    // 0..32767
    const int db = w >> 13, i = w & (NPTS - 1);
    const float* p = part + ((size_t)db * NSPLIT) * NPTS + i;
    float m = p[0];
    #pragma unroll
    for (int s = 1; s < NSPLIT; ++s) m = fminf(m, p[(size_t)s * NPTS]);
    out[w] = fmaxf(m, 0.f);
}

extern "C" void kernel_launch(void* const* d_in, const int* in_sizes, int n_in,
                              void* d_out, int out_size, void* d_ws, size_t ws_size,
                              hipStream_t stream) {
    const float* x = (const float*)d_in[0];
    const float* y = (const float*)d_in[1];
    float* part = (float*)d_ws;          // 4 db x 8 splits x 8192 = 1 MiB
    float* out  = (float*)d_out;

    _chamfer_main<<<dim3(32, 4, NSPLIT), dim3(256), 0, stream>>>(x, y, part);
    _chamfer_reduce<<<dim3(out_size / 256), dim3(256), 0, stream>>>(part, out);
}